// Round 11
// baseline (156.894 us; speedup 1.0000x reference)
//
#include <hip/hip_runtime.h>
#include <math.h>

// Problem constants
#define Bn   8
#define Cc   256     // input channels
#define Cin  128     // inter channels
#define Hh   64
#define Ww   64
#define Nn   4096    // H*W
#define Npl  1024    // pooled pixels (32*32)
#define EPSf 1e-5f

typedef __attribute__((ext_vector_type(8))) short    short8;   // 8 bf16
typedef __attribute__((ext_vector_type(8))) _Float16 half8;    // 8 fp16
typedef __attribute__((ext_vector_type(4))) float    floatx4;  // MFMA C/D

__device__ __forceinline__ unsigned short f2bf(float f) {
    unsigned int u = __float_as_uint(f);
    u += 0x7fffu + ((u >> 16) & 1u);
    return (unsigned short)(u >> 16);
}
__device__ __forceinline__ unsigned short f2h(float f) {
    _Float16 h = (_Float16)f;
    return __builtin_bit_cast(unsigned short, h);
}
__device__ __forceinline__ float h2f(unsigned short u) {
    return (float)__builtin_bit_cast(_Float16, u);
}

// pack two f32 -> bf16 pair (lo=src0, hi=src1); no builtin on gfx950
__device__ __forceinline__ unsigned int cvtpk_bf16(float lo, float hi) {
    unsigned int r;
    asm("v_cvt_pk_bf16_f32 %0, %1, %2" : "=v"(r) : "v"(lo), "v"(hi));
    return r;
}

// async global->LDS DMA, 16B per lane; LDS dest = wave-uniform base + lane*16
__device__ __forceinline__ void gload_lds16(const unsigned short* g, unsigned short* l) {
    __builtin_amdgcn_global_load_lds(
        (const __attribute__((address_space(1))) unsigned int*)g,
        (__attribute__((address_space(3))) unsigned int*)l, 16, 0, 0);
}

// ---------------------------------------------------------------------------
// Kernel 0 (prep): fp16 weight variants.
//  - g/theta/phi stored PRE-PERMUTED into MFMA A-fragment order (R15).
//  - Wh = fp16(W_w * gamma/sqrt(var+eps)) row-major; cvec folded BN bias.
// ---------------------------------------------------------------------------
__global__ __launch_bounds__(256) void k_prep(
    const float* __restrict__ g_w, const float* __restrict__ th_w,
    const float* __restrict__ ph_w,
    const float* __restrict__ W_w, const float* __restrict__ W_b,
    const float* __restrict__ gamma, const float* __restrict__ beta,
    const float* __restrict__ mean,  const float* __restrict__ var,
    unsigned short* __restrict__ gWh,
    unsigned short* __restrict__ thWh, unsigned short* __restrict__ thWl,
    unsigned short* __restrict__ phWh, unsigned short* __restrict__ phWl,
    unsigned short* __restrict__ Wh, float* __restrict__ cvec)
{
    int i = blockIdx.x * 256 + threadIdx.x;
    if (i < 98304) {                          // 3 x 128 x 256 conv weights
        int seg = i >> 15;                    // 0:g 1:theta 2:phi
        int idx = i & 32767;
        int o = idx >> 8;                     // 0..127 output channel
        int c = idx & 255;                    // 0..255 input channel
        // fragment-order position (bijective)
        int p = (((o >> 4) * 8 + (c >> 5)) * 64
                 + ((c >> 3) & 3) * 16 + (o & 15)) * 8 + (c & 7);
        float v = (seg == 0 ? g_w : (seg == 1 ? th_w : ph_w))[idx];
        unsigned short hi = f2h(v);
        if (seg == 0) gWh[p] = hi;
        else {
            (seg == 1 ? thWh : phWh)[p] = hi;
            (seg == 1 ? thWl : phWl)[p] = f2h(v - h2f(hi));
        }
    } else {
        int j = i - 98304;                    // 0..32767 : W fold (256x128)
        int o = j >> 7;
        float inv = gamma[o] * rsqrtf(var[o] + EPSf);
        Wh[j] = f2h(W_w[j] * inv);
        if (j < Cc) {
            float invi = gamma[j] * rsqrtf(var[j] + EPSf);
            cvec[j] = (W_b[j] - mean[j]) * invi + beta[j];
        }
    }
}

// ---------------------------------------------------------------------------
// Kernel 1 (R18, proven: off top-5, ~20us): fused conv1x1 g/theta/phi,
// 64-px tiles, 512 threads / 8 waves each owning 3 of 24 output-tiles
// (ot = w + 8*ti, seg == ti). 16 waves/CU. Weights in fragment order.
// ---------------------------------------------------------------------------
#define XPAD 264

__global__ __launch_bounds__(512, 4) void k_conv3(
    const float* __restrict__ x,
    const unsigned short* __restrict__ gWh,
    const unsigned short* __restrict__ thWh, const unsigned short* __restrict__ thWl,
    const unsigned short* __restrict__ phWh, const unsigned short* __restrict__ phWl,
    const float* __restrict__ g_b, const float* __restrict__ th_b,
    const float* __restrict__ ph_b,
    unsigned short* __restrict__ thetaT,
    unsigned short* __restrict__ gPc,
    unsigned short* __restrict__ phiPt)
{
    __shared__ __align__(16) unsigned short Xhi[64 * XPAD];   // 33 KB
    __shared__ __align__(16) unsigned short Xlo[64 * XPAD];   // 33 KB

    const int t    = threadIdx.x;
    const int w    = t >> 6;          // 0..7
    const int l    = t & 63;
    const int quad = l >> 4;
    const int l16  = l & 15;
    const int b    = blockIdx.x >> 6;
    const int tile = blockIdx.x & 63;
    const int ty   = tile >> 1;
    const int tx   = tile & 1;

    {
        const float4* xg = (const float4*)x;
        unsigned int* XhiW = (unsigned int*)Xhi;
        unsigned int* XloW = (unsigned int*)Xlo;
        #pragma unroll
        for (int it = 0; it < 4; ++it) {
            int idx = t + 512 * it;          // 0..2047
            int c2  = idx >> 4;
            int p4  = idx & 15;
            int n   = (2 * ty + (p4 >> 3)) * Ww + tx * 32 + (p4 & 7) * 4;
            float4 va = xg[((size_t)(b * Cc + 2 * c2) * Nn + n) >> 2];
            float4 vb = xg[((size_t)(b * Cc + 2 * c2 + 1) * Nn + n) >> 2];
            const float fa[4] = {va.x, va.y, va.z, va.w};
            const float fb[4] = {vb.x, vb.y, vb.z, vb.w};
            #pragma unroll
            for (int i = 0; i < 4; ++i) {
                int px = p4 * 4 + i;
                unsigned short ha = f2h(fa[i]), hb = f2h(fb[i]);
                unsigned short la = f2h(fa[i] - h2f(ha));
                unsigned short lb = f2h(fb[i] - h2f(hb));
                XhiW[px * 132 + c2] = (unsigned int)ha | ((unsigned int)hb << 16);
                XloW[px * 132 + c2] = (unsigned int)la | ((unsigned int)lb << 16);
            }
        }
    }
    __syncthreads();

    floatx4 acc[3][4] = {};

    #pragma unroll 2
    for (int kd = 0; kd < 8; ++kd) {
        half8 bhi[4], blo[4];
        #pragma unroll
        for (int nt = 0; nt < 4; ++nt) {
            bhi[nt] = *(const half8*)&Xhi[(nt * 16 + l16) * XPAD + kd * 32 + quad * 8];
            blo[nt] = *(const half8*)&Xlo[(nt * 16 + l16) * XPAD + kd * 32 + quad * 8];
        }
        #pragma unroll
        for (int ti = 0; ti < 3; ++ti) {
            int seg = ti;                                // ot = w + 8*ti
            size_t aoff = (size_t)((w * 8 + kd) * 512 + l * 8);   // frag order
            const unsigned short* wh = (seg == 0 ? gWh : (seg == 1 ? thWh : phWh));
            half8 ah = *(const half8*)&wh[aoff];
            #pragma unroll
            for (int nt = 0; nt < 4; ++nt)
                acc[ti][nt] = __builtin_amdgcn_mfma_f32_16x16x32_f16(ah, bhi[nt], acc[ti][nt], 0, 0, 0);
            if (seg != 0) {
                const unsigned short* wl = (seg == 1 ? thWl : phWl);
                half8 al = *(const half8*)&wl[aoff];
                #pragma unroll
                for (int nt = 0; nt < 4; ++nt) {
                    acc[ti][nt] = __builtin_amdgcn_mfma_f32_16x16x32_f16(ah, blo[nt], acc[ti][nt], 0, 0, 0);
                    acc[ti][nt] = __builtin_amdgcn_mfma_f32_16x16x32_f16(al, bhi[nt], acc[ti][nt], 0, 0, 0);
                }
            }
        }
    }

    // epilogue: D[row=quad*4+r][col=l16]; per wave channels w*16+quad*4..+3
    #pragma unroll
    for (int ti = 0; ti < 3; ++ti) {
        int seg = ti;
        int ol  = w * 16 + quad * 4;
        if (seg == 1) {                            // theta -> fp16 [n][o]
            float b0 = th_b[ol], b1 = th_b[ol + 1], b2 = th_b[ol + 2], b3 = th_b[ol + 3];
            #pragma unroll
            for (int nt = 0; nt < 4; ++nt) {
                int n = (2 * ty + (nt >> 1)) * Ww + tx * 32 + (nt & 1) * 16 + l16;
                ushort4 v;
                v.x = f2h(acc[ti][nt][0] + b0);
                v.y = f2h(acc[ti][nt][1] + b1);
                v.z = f2h(acc[ti][nt][2] + b2);
                v.w = f2h(acc[ti][nt][3] + b3);
                *(ushort4*)&thetaT[((size_t)b * Nn + n) * Cin + ol] = v;
            }
        } else {                                   // g / phi: 2x2 maxpool
            const float* bb = (seg == 0 ? g_b : ph_b);
            float b0 = bb[ol], b1 = bb[ol + 1], b2 = bb[ol + 2], b3 = bb[ol + 3];
            #pragma unroll
            for (int pp = 0; pp < 2; ++pp) {
                float pm[4];
                #pragma unroll
                for (int r = 0; r < 4; ++r) {
                    float m = fmaxf(acc[ti][pp][r], acc[ti][pp + 2][r]);
                    pm[r] = fmaxf(m, __shfl_xor(m, 1, 64));
                }
                int np = ty * 32 + tx * 16 + pp * 8 + (l16 >> 1);
                if ((l16 & 1) == 0) {
                    if (seg == 0) {                // g -> bf16 [o][np] (V dtype)
                        gPc[((size_t)b * Cin + ol + 0) * Npl + np] = f2bf(pm[0] + b0);
                        gPc[((size_t)b * Cin + ol + 1) * Npl + np] = f2bf(pm[1] + b1);
                        gPc[((size_t)b * Cin + ol + 2) * Npl + np] = f2bf(pm[2] + b2);
                        gPc[((size_t)b * Cin + ol + 3) * Npl + np] = f2bf(pm[3] + b3);
                    } else {                       // phi -> fp16 [np][o]
                        ushort4 v;
                        v.x = f2h(pm[0] + b0); v.y = f2h(pm[1] + b1);
                        v.z = f2h(pm[2] + b2); v.w = f2h(pm[3] + b3);
                        *(ushort4*)&phiPt[((size_t)b * Npl + np) * Cin + ol] = v;
                    }
                }
            }
        }
    }
}

// ---------------------------------------------------------------------------
// stage one shared 64-key chunk into buffer sel: waves 0-3 -> K, 4-7 -> V^T.
// ---------------------------------------------------------------------------
__device__ __forceinline__ void stage_kv(
    unsigned short* smem, int sel, int chg, int b, int grp, int wq,
    int mK, int gK, int cV, int gV,
    const unsigned short* __restrict__ phiPt,
    const unsigned short* __restrict__ gPc)
{
    unsigned short* Kb = smem + sel * 16384;
    if (grp == 0) {
        #pragma unroll
        for (int j = 0; j < 4; ++j) {
            int slot = wq * 4 + j;            // 16 slots x 1KB (4 key rows)
            int m  = slot * 4 + mK;
            int gs = gK ^ (m & 7);            // swizzled SOURCE granule
            gload_lds16(&phiPt[((size_t)b * Npl + chg * 64 + m) * Cin + gs * 8],
                        &Kb[slot * 512]);
        }
    } else {
        unsigned short* Vb = Kb + 8192;
        #pragma unroll
        for (int j = 0; j < 4; ++j) {
            int slot = wq * 4 + j;            // 16 slots x 1KB (8 chan rows)
            int c  = slot * 8 + cV;
            int gs = gV ^ (c & 7);
            gload_lds16(&gPc[((size_t)b * Cin + c) * Npl + chg * 64 + gs * 8],
                        &Vb[slot * 512]);
        }
    }
}

// ---------------------------------------------------------------------------
// Kernel 2 (R19): fused attention + W conv + BN + residual, 512 threads,
// 128 QUERIES per block (2 q-tiles per wave). kf/vf fragments are loaded
// once and feed TWO MFMAs each -> per-CU LDS read traffic HALVES (was the
// dominant floor; kf/vf were 4x-duplicated across a group's waves and the
// ratio was 16 reads : 16 MFMA -> now 16 : 32). Grid 256 -> 1 block/CU;
// the freed LDS funds 4 K/V buffers (128 KB) + R17's field-proven counted
// vmcnt ledger (steady vmcnt(8), tail 4->0) to hide DMA latency at low TLP.
// Phase 2: Ys 32 KB + Ws 64 KB = 96 KB; cbuf 67.6 KB over dead buffers.
// ---------------------------------------------------------------------------
#define SSHIFT 20.0f

__global__ __launch_bounds__(512, 2) void k_attn_out(
    const unsigned short* __restrict__ thetaT,
    const unsigned short* __restrict__ phiPt,
    const unsigned short* __restrict__ gPc,
    const unsigned short* __restrict__ Wh,
    const float* __restrict__ cvec,
    const float* __restrict__ x,
    float* __restrict__ out)
{
    __shared__ __align__(16) unsigned short smem[65536];   // 128 KB
    // phase 1: buf[sel] = smem + sel*16384 shorts (Ks 16KB + Vt 16KB), sel=ch&3
    // combine: cbuf f32[8*64*33] = 67.6 KB over dead bufs
    // phase 2: Ys = smem[0..16384) shorts (32KB), Ws = smem+16384 (64KB)

    const int t    = threadIdx.x;
    const int w    = t >> 6;          // 0..7
    const int wq   = w & 3;           // query 32-block
    const int grp  = w >> 2;          // key half within chunk
    const int l    = t & 63;
    const int quad = l >> 4;
    const int l16  = l & 15;
    const int bid  = blockIdx.x;
    const int wid  = (bid & 7) * 32 + (bid >> 3);   // batch b -> XCD b (256=8*32)
    const int b    = wid >> 5;
    const int qb   = wid & 31;
    const int n0   = qb * 128;

    // Q fragments for 2 q-tiles, loaded ONCE; asm pins in VGPRs
    uint4 qr0[4], qr1[4];
    #pragma unroll
    for (int kd = 0; kd < 4; ++kd) {
        qr0[kd] = *(const uint4*)&thetaT[((size_t)b * Nn + n0 + wq * 32 + l16) * Cin
                                         + kd * 32 + quad * 8];
        qr1[kd] = *(const uint4*)&thetaT[((size_t)b * Nn + n0 + wq * 32 + 16 + l16) * Cin
                                         + kd * 32 + quad * 8];
    }
    #pragma unroll
    for (int kd = 0; kd < 4; ++kd) {
        asm volatile("" : "+v"(qr0[kd].x), "+v"(qr0[kd].y), "+v"(qr0[kd].z), "+v"(qr0[kd].w));
        asm volatile("" : "+v"(qr1[kd].x), "+v"(qr1[kd].y), "+v"(qr1[kd].z), "+v"(qr1[kd].w));
    }
    half8 qf0[4], qf1[4];
    #pragma unroll
    for (int kd = 0; kd < 4; ++kd) {
        qf0[kd] = __builtin_bit_cast(half8, qr0[kd]);
        qf1[kd] = __builtin_bit_cast(half8, qr1[kd]);
    }

    floatx4 yacc0[8] = {}, yacc1[8] = {};
    float liq0 = 0.f, liq1 = 0.f;

    const int mK = l >> 4;            // staging lane decomposition
    const int gK = l & 15;
    const int cV = l >> 3;
    const int gV = l & 7;

    // prologue: stage chunks 0,1,2 (12 issues/wave after 8 Q loads)
    #pragma unroll
    for (int pc = 0; pc < 3; ++pc)
        stage_kv(smem, pc, pc, b, grp, wq, mK, gK, cV, gV, phiPt, gPc);
    asm volatile("s_waitcnt vmcnt(8)" ::: "memory");   // chunk0 (and Q) retired
    __builtin_amdgcn_s_barrier();

    for (int ch = 0; ch < 16; ++ch) {
        if (ch < 13)                              // prefetch 3 chunks ahead
            stage_kv(smem, (ch + 3) & 3, ch + 3, b, grp, wq, mK, gK, cV, gV, phiPt, gPc);

        const unsigned short* Ks = smem + (ch & 3) * 16384;
        const unsigned short* Vt = Ks + 8192;

        // S^T = K Q^T, group's 32 keys x both q-tiles; kf REUSED across qt
        floatx4 sacc0[2] = {}, sacc1[2] = {};
        #pragma unroll
        for (int mtl = 0; mtl < 2; ++mtl) {
            int mt = grp * 2 + mtl;
            #pragma unroll
            for (int kd = 0; kd < 4; ++kd) {
                half8 kf = *(const half8*)&Ks[(mt * 16 + l16) * 128
                                              + (((kd * 4 + quad) ^ (l16 & 7)) << 3)];
                sacc0[mtl] = __builtin_amdgcn_mfma_f32_16x16x32_f16(kf, qf0[kd], sacc0[mtl], 0, 0, 0);
                sacc1[mtl] = __builtin_amdgcn_mfma_f32_16x16x32_f16(kf, qf1[kd], sacc1[mtl], 0, 0, 0);
            }
        }

        // P = exp(S^T - SSHIFT) per q-tile; in-register redistribution
        short8 pf0, pf1;
        {
            float e0[4], e1[4];
            #pragma unroll
            for (int r = 0; r < 4; ++r) {
                e0[r] = __expf(sacc0[0][r] - SSHIFT);
                e1[r] = __expf(sacc0[1][r] - SSHIFT);
                liq0 += e0[r] + e1[r];
            }
            unsigned int a0 = cvtpk_bf16(e0[0], e0[1]);
            unsigned int a1 = cvtpk_bf16(e1[0], e1[1]);
            unsigned int b0 = cvtpk_bf16(e0[2], e0[3]);
            unsigned int b1 = cvtpk_bf16(e1[2], e1[3]);
            asm volatile("v_permlane32_swap_b32 %0, %1" : "+v"(a0), "+v"(a1));
            asm volatile("v_permlane16_swap_b32 %0, %1" : "+v"(a0), "+v"(a1));
            asm volatile("v_permlane32_swap_b32 %0, %1" : "+v"(b0), "+v"(b1));
            asm volatile("v_permlane16_swap_b32 %0, %1" : "+v"(b0), "+v"(b1));
            uint4 pw; pw.x = a0; pw.y = b0; pw.z = a1; pw.w = b1;
            pf0 = __builtin_bit_cast(short8, pw);
        }
        {
            float e0[4], e1[4];
            #pragma unroll
            for (int r = 0; r < 4; ++r) {
                e0[r] = __expf(sacc1[0][r] - SSHIFT);
                e1[r] = __expf(sacc1[1][r] - SSHIFT);
                liq1 += e0[r] + e1[r];
            }
            unsigned int a0 = cvtpk_bf16(e0[0], e0[1]);
            unsigned int a1 = cvtpk_bf16(e1[0], e1[1]);
            unsigned int b0 = cvtpk_bf16(e0[2], e0[3]);
            unsigned int b1 = cvtpk_bf16(e1[2], e1[3]);
            asm volatile("v_permlane32_swap_b32 %0, %1" : "+v"(a0), "+v"(a1));
            asm volatile("v_permlane16_swap_b32 %0, %1" : "+v"(a0), "+v"(a1));
            asm volatile("v_permlane32_swap_b32 %0, %1" : "+v"(b0), "+v"(b1));
            asm volatile("v_permlane16_swap_b32 %0, %1" : "+v"(b0), "+v"(b1));
            uint4 pw; pw.x = a0; pw.y = b0; pw.z = a1; pw.w = b1;
            pf1 = __builtin_bit_cast(short8, pw);
        }

        // Y += P V at key-depth grp: vf REUSED across both q-tiles
        #pragma unroll
        for (int ct = 0; ct < 8; ++ct) {
            short8 vf = *(const short8*)&Vt[(ct * 16 + l16) * 64
                                            + (((grp * 4 + quad) ^ (l16 & 7)) << 3)];
            yacc0[ct] = __builtin_amdgcn_mfma_f32_16x16x32_bf16(pf0, vf, yacc0[ct], 0, 0, 0);
            yacc1[ct] = __builtin_amdgcn_mfma_f32_16x16x32_bf16(pf1, vf, yacc1[ct], 0, 0, 0);
        }

        // counted publish of chunk ch+1 (never drain to 0 mid-loop)
        if (ch < 13)       asm volatile("s_waitcnt vmcnt(8)" ::: "memory");
        else if (ch == 13) asm volatile("s_waitcnt vmcnt(4)" ::: "memory");
        else if (ch == 14) asm volatile("s_waitcnt vmcnt(0)" ::: "memory");
        __builtin_amdgcn_s_barrier();
    }

    // ------- cross-group combine (once) -------
    liq0 += __shfl_xor(liq0, 16, 64);
    liq0 += __shfl_xor(liq0, 32, 64);
    liq1 += __shfl_xor(liq1, 16, 64);
    liq1 += __shfl_xor(liq1, 32, 64);

    float* cbuf = (float*)smem;
    const int ci0 = ((wq * 2 + 0) * 64 + l) * 33;   // pad 33 -> 2-way banks
    const int ci1 = ((wq * 2 + 1) * 64 + l) * 33;
    if (grp == 1) {
        #pragma unroll
        for (int ct = 0; ct < 8; ++ct)
            #pragma unroll
            for (int r = 0; r < 4; ++r) {
                cbuf[ci0 + ct * 4 + r] = yacc0[ct][r];
                cbuf[ci1 + ct * 4 + r] = yacc1[ct][r];
            }
        cbuf[ci0 + 32] = liq0;
        cbuf[ci1 + 32] = liq1;
    }
    __syncthreads();
    if (grp == 0) {
        #pragma unroll
        for (int ct = 0; ct < 8; ++ct)
            #pragma unroll
            for (int r = 0; r < 4; ++r) {
                yacc0[ct][r] += cbuf[ci0 + ct * 4 + r];
                yacc1[ct][r] += cbuf[ci1 + ct * 4 + r];
            }
        liq0 += cbuf[ci0 + 32];
        liq1 += cbuf[ci1 + 32];
    }
    __syncthreads();                          // combine region dead

    // ------- phase 2: out = Wh @ y + cvec + x -------
    // stage full Wh (256x128 fp16, 64 KB) via DMA at smem+16384
    {
        unsigned short* Ws = smem + 16384;
        #pragma unroll
        for (int j = 0; j < 8; ++j) {
            int slot = w * 8 + j;             // 0..63, 4 rows each
            int row  = slot * 4 + mK;         // 0..255
            int gs   = gK ^ (row & 7);
            gload_lds16(&Wh[(size_t)row * Cin + gs * 8], &Ws[slot * 512]);
        }
    }

    // normalized y -> Ys fp16 [128 q][128 c] (group 0), packed 4B writes
    if (grp == 0) {
        unsigned int* Yw = (unsigned int*)smem;
        #pragma unroll
        for (int r = 0; r < 4; ++r) {
            float lr0 = __shfl(liq0, quad * 4 + r, 64);
            float lr1 = __shfl(liq1, quad * 4 + r, 64);
            float il0 = 1.0f / lr0;
            float il1 = 1.0f / lr1;
            int q0 = wq * 32 + quad * 4 + r;
            int q1 = q0 + 16;
            #pragma unroll
            for (int ct = 0; ct < 8; ++ct) {
                unsigned int h0 = f2h(yacc0[ct][r] * il0);
                unsigned int p0 = (unsigned int)__shfl_xor((int)h0, 1, 64);
                unsigned int h1 = f2h(yacc1[ct][r] * il1);
                unsigned int p1 = (unsigned int)__shfl_xor((int)h1, 1, 64);
                if ((l16 & 1) == 0) {
                    int g = ct * 2 + (l16 >> 3);
                    Yw[q0 * 64 + (((g ^ (q0 & 7)) << 2) | ((l16 & 7) >> 1))] = h0 | (p0 << 16);
                    Yw[q1 * 64 + (((g ^ (q1 & 7)) << 2) | ((l16 & 7) >> 1))] = h1 | (p1 << 16);
                }
            }
        }
    }
    asm volatile("s_waitcnt vmcnt(0)" ::: "memory");
    __syncthreads();

    const unsigned short* Ys = smem;
    const unsigned short* Ws = smem + 16384;

    // each wave: 32 output rows (w*32..+31) x 128 queries (8 nt tiles)
    half8 af[2][4];
    #pragma unroll
    for (int mt = 0; mt < 2; ++mt)
        #pragma unroll
        for (int kd = 0; kd < 4; ++kd) {
            int row = w * 32 + mt * 16 + l16;
            af[mt][kd] = *(const half8*)&Ws[row * 128
                                            + (((kd * 4 + quad) ^ (l16 & 7)) << 3)];
        }

    floatx4 acc[2][8] = {};
    #pragma unroll
    for (int nt = 0; nt < 8; ++nt) {
        half8 bfr[4];
        #pragma unroll
        for (int kd = 0; kd < 4; ++kd)
            bfr[kd] = *(const half8*)&Ys[(nt * 16 + l16) * 128
                                         + (((kd * 4 + quad) ^ (l16 & 7)) << 3)];
        #pragma unroll
        for (int mt = 0; mt < 2; ++mt)
            #pragma unroll
            for (int kd = 0; kd < 4; ++kd)
                acc[mt][nt] = __builtin_amdgcn_mfma_f32_16x16x32_f16(af[mt][kd], bfr[kd], acc[mt][nt], 0, 0, 0);
    }

    #pragma unroll
    for (int mt = 0; mt < 2; ++mt) {
        #pragma unroll
        for (int r = 0; r < 4; ++r) {
            int o = w * 32 + mt * 16 + quad * 4 + r;
            float cv = cvec[o];
            #pragma unroll
            for (int nt = 0; nt < 8; ++nt) {
                size_t gi = ((size_t)(b * Cc + o)) * Nn + n0 + nt * 16 + l16;
                out[gi] = acc[mt][nt][r] + cv + x[gi];
            }
        }
    }
}

// ---------------------------------------------------------------------------
extern "C" void kernel_launch(void* const* d_in, const int* in_sizes, int n_in,
                              void* d_out, int out_size, void* d_ws, size_t ws_size,
                              hipStream_t stream) {
    const float* x    = (const float*)d_in[0];
    const float* g_w  = (const float*)d_in[1];
    const float* g_b  = (const float*)d_in[2];
    const float* th_w = (const float*)d_in[3];
    const float* th_b = (const float*)d_in[4];
    const float* ph_w = (const float*)d_in[5];
    const float* ph_b = (const float*)d_in[6];
    const float* W_w  = (const float*)d_in[7];
    const float* W_b  = (const float*)d_in[8];
    const float* gmm  = (const float*)d_in[9];
    const float* bta  = (const float*)d_in[10];
    const float* mmn  = (const float*)d_in[11];
    const float* vvr  = (const float*)d_in[12];
    float* out = (float*)d_out;

    unsigned short* thetaT = (unsigned short*)d_ws;      // 8 MB fp16
    unsigned short* phiPt  = thetaT + (size_t)4194304;   // 2 MB fp16
    unsigned short* gPc    = phiPt + (size_t)1048576;    // 2 MB bf16
    unsigned short* Wh     = gPc + (size_t)1048576;      // 64 KB
    unsigned short* gWh    = Wh + 32768;
    unsigned short* thWh   = gWh + 32768;
    unsigned short* thWl   = thWh + 32768;
    unsigned short* phWh   = thWl + 32768;
    unsigned short* phWl   = phWh + 32768;
    float*          cvec   = (float*)(phWl + 32768);     // 1 KB

    k_prep<<<dim3(512), dim3(256), 0, stream>>>(
        g_w, th_w, ph_w, W_w, W_b, gmm, bta, mmn, vvr,
        gWh, thWh, thWl, phWh, phWl, Wh, cvec);
    k_conv3<<<dim3(Bn * 64), dim3(512), 0, stream>>>(
        x, gWh, thWh, thWl, phWh, phWl, g_b, th_b, ph_b, thetaT, gPc, phiPt);
    k_attn_out<<<dim3(Bn * 32), dim3(512), 0, stream>>>(
        thetaT, phiPt, gPc, Wh, cvec, x, out);
}

// Round 12
// 154.382 us; speedup vs baseline: 1.0163x; 1.0163x over previous
//
#include <hip/hip_runtime.h>
#include <math.h>

// Problem constants
#define Bn   8
#define Cc   256     // input channels
#define Cin  128     // inter channels
#define Hh   64
#define Ww   64
#define Nn   4096    // H*W
#define Npl  1024    // pooled pixels (32*32)
#define EPSf 1e-5f

typedef __attribute__((ext_vector_type(8))) short    short8;   // 8 bf16
typedef __attribute__((ext_vector_type(8))) _Float16 half8;    // 8 fp16
typedef __attribute__((ext_vector_type(4))) float    floatx4;  // MFMA C/D

__device__ __forceinline__ unsigned short f2bf(float f) {
    unsigned int u = __float_as_uint(f);
    u += 0x7fffu + ((u >> 16) & 1u);
    return (unsigned short)(u >> 16);
}
__device__ __forceinline__ unsigned short f2h(float f) {
    _Float16 h = (_Float16)f;
    return __builtin_bit_cast(unsigned short, h);
}
__device__ __forceinline__ float h2f(unsigned short u) {
    return (float)__builtin_bit_cast(_Float16, u);
}

// pack two f32 -> bf16 pair (lo=src0, hi=src1); no builtin on gfx950
__device__ __forceinline__ unsigned int cvtpk_bf16(float lo, float hi) {
    unsigned int r;
    asm("v_cvt_pk_bf16_f32 %0, %1, %2" : "=v"(r) : "v"(lo), "v"(hi));
    return r;
}

// async global->LDS DMA, 16B per lane; LDS dest = wave-uniform base + lane*16
__device__ __forceinline__ void gload_lds16(const unsigned short* g, unsigned short* l) {
    __builtin_amdgcn_global_load_lds(
        (const __attribute__((address_space(1))) unsigned int*)g,
        (__attribute__((address_space(3))) unsigned int*)l, 16, 0, 0);
}

// ---------------------------------------------------------------------------
// Kernel 0 (prep): fp16 weight variants.
//  - g/theta/phi stored PRE-PERMUTED into MFMA A-fragment order (R15).
//  - Wh = fp16(W_w * gamma/sqrt(var+eps)) row-major; cvec folded BN bias.
// ---------------------------------------------------------------------------
__global__ __launch_bounds__(256) void k_prep(
    const float* __restrict__ g_w, const float* __restrict__ th_w,
    const float* __restrict__ ph_w,
    const float* __restrict__ W_w, const float* __restrict__ W_b,
    const float* __restrict__ gamma, const float* __restrict__ beta,
    const float* __restrict__ mean,  const float* __restrict__ var,
    unsigned short* __restrict__ gWh,
    unsigned short* __restrict__ thWh, unsigned short* __restrict__ thWl,
    unsigned short* __restrict__ phWh, unsigned short* __restrict__ phWl,
    unsigned short* __restrict__ Wh, float* __restrict__ cvec)
{
    int i = blockIdx.x * 256 + threadIdx.x;
    if (i < 98304) {                          // 3 x 128 x 256 conv weights
        int seg = i >> 15;                    // 0:g 1:theta 2:phi
        int idx = i & 32767;
        int o = idx >> 8;                     // 0..127 output channel
        int c = idx & 255;                    // 0..255 input channel
        // fragment-order position (bijective)
        int p = (((o >> 4) * 8 + (c >> 5)) * 64
                 + ((c >> 3) & 3) * 16 + (o & 15)) * 8 + (c & 7);
        float v = (seg == 0 ? g_w : (seg == 1 ? th_w : ph_w))[idx];
        unsigned short hi = f2h(v);
        if (seg == 0) gWh[p] = hi;
        else {
            (seg == 1 ? thWh : phWh)[p] = hi;
            (seg == 1 ? thWl : phWl)[p] = f2h(v - h2f(hi));
        }
    } else {
        int j = i - 98304;                    // 0..32767 : W fold (256x128)
        int o = j >> 7;
        float inv = gamma[o] * rsqrtf(var[o] + EPSf);
        Wh[j] = f2h(W_w[j] * inv);
        if (j < Cc) {
            float invi = gamma[j] * rsqrtf(var[j] + EPSf);
            cvec[j] = (W_b[j] - mean[j]) * invi + beta[j];
        }
    }
}

// ---------------------------------------------------------------------------
// Kernel 1 (R18, proven): fused conv1x1 g/theta/phi, 64-px tiles, 512
// threads / 8 waves each owning 3 of 24 output-tiles (ot = w + 8*ti,
// seg == ti). 16 waves/CU. Weights in fragment order.
// ---------------------------------------------------------------------------
#define XPAD 264

__global__ __launch_bounds__(512, 4) void k_conv3(
    const float* __restrict__ x,
    const unsigned short* __restrict__ gWh,
    const unsigned short* __restrict__ thWh, const unsigned short* __restrict__ thWl,
    const unsigned short* __restrict__ phWh, const unsigned short* __restrict__ phWl,
    const float* __restrict__ g_b, const float* __restrict__ th_b,
    const float* __restrict__ ph_b,
    unsigned short* __restrict__ thetaT,
    unsigned short* __restrict__ gPc,
    unsigned short* __restrict__ phiPt)
{
    __shared__ __align__(16) unsigned short Xhi[64 * XPAD];   // 33 KB
    __shared__ __align__(16) unsigned short Xlo[64 * XPAD];   // 33 KB

    const int t    = threadIdx.x;
    const int w    = t >> 6;          // 0..7
    const int l    = t & 63;
    const int quad = l >> 4;
    const int l16  = l & 15;
    const int b    = blockIdx.x >> 6;
    const int tile = blockIdx.x & 63;
    const int ty   = tile >> 1;
    const int tx   = tile & 1;

    {
        const float4* xg = (const float4*)x;
        unsigned int* XhiW = (unsigned int*)Xhi;
        unsigned int* XloW = (unsigned int*)Xlo;
        #pragma unroll
        for (int it = 0; it < 4; ++it) {
            int idx = t + 512 * it;          // 0..2047
            int c2  = idx >> 4;
            int p4  = idx & 15;
            int n   = (2 * ty + (p4 >> 3)) * Ww + tx * 32 + (p4 & 7) * 4;
            float4 va = xg[((size_t)(b * Cc + 2 * c2) * Nn + n) >> 2];
            float4 vb = xg[((size_t)(b * Cc + 2 * c2 + 1) * Nn + n) >> 2];
            const float fa[4] = {va.x, va.y, va.z, va.w};
            const float fb[4] = {vb.x, vb.y, vb.z, vb.w};
            #pragma unroll
            for (int i = 0; i < 4; ++i) {
                int px = p4 * 4 + i;
                unsigned short ha = f2h(fa[i]), hb = f2h(fb[i]);
                unsigned short la = f2h(fa[i] - h2f(ha));
                unsigned short lb = f2h(fb[i] - h2f(hb));
                XhiW[px * 132 + c2] = (unsigned int)ha | ((unsigned int)hb << 16);
                XloW[px * 132 + c2] = (unsigned int)la | ((unsigned int)lb << 16);
            }
        }
    }
    __syncthreads();

    floatx4 acc[3][4] = {};

    #pragma unroll 2
    for (int kd = 0; kd < 8; ++kd) {
        half8 bhi[4], blo[4];
        #pragma unroll
        for (int nt = 0; nt < 4; ++nt) {
            bhi[nt] = *(const half8*)&Xhi[(nt * 16 + l16) * XPAD + kd * 32 + quad * 8];
            blo[nt] = *(const half8*)&Xlo[(nt * 16 + l16) * XPAD + kd * 32 + quad * 8];
        }
        #pragma unroll
        for (int ti = 0; ti < 3; ++ti) {
            int seg = ti;                                // ot = w + 8*ti
            size_t aoff = (size_t)((w * 8 + kd) * 512 + l * 8);   // frag order
            const unsigned short* wh = (seg == 0 ? gWh : (seg == 1 ? thWh : phWh));
            half8 ah = *(const half8*)&wh[aoff];
            #pragma unroll
            for (int nt = 0; nt < 4; ++nt)
                acc[ti][nt] = __builtin_amdgcn_mfma_f32_16x16x32_f16(ah, bhi[nt], acc[ti][nt], 0, 0, 0);
            if (seg != 0) {
                const unsigned short* wl = (seg == 1 ? thWl : phWl);
                half8 al = *(const half8*)&wl[aoff];
                #pragma unroll
                for (int nt = 0; nt < 4; ++nt) {
                    acc[ti][nt] = __builtin_amdgcn_mfma_f32_16x16x32_f16(ah, blo[nt], acc[ti][nt], 0, 0, 0);
                    acc[ti][nt] = __builtin_amdgcn_mfma_f32_16x16x32_f16(al, bhi[nt], acc[ti][nt], 0, 0, 0);
                }
            }
        }
    }

    // epilogue: D[row=quad*4+r][col=l16]; per wave channels w*16+quad*4..+3
    #pragma unroll
    for (int ti = 0; ti < 3; ++ti) {
        int seg = ti;
        int ol  = w * 16 + quad * 4;
        if (seg == 1) {                            // theta -> fp16 [n][o]
            float b0 = th_b[ol], b1 = th_b[ol + 1], b2 = th_b[ol + 2], b3 = th_b[ol + 3];
            #pragma unroll
            for (int nt = 0; nt < 4; ++nt) {
                int n = (2 * ty + (nt >> 1)) * Ww + tx * 32 + (nt & 1) * 16 + l16;
                ushort4 v;
                v.x = f2h(acc[ti][nt][0] + b0);
                v.y = f2h(acc[ti][nt][1] + b1);
                v.z = f2h(acc[ti][nt][2] + b2);
                v.w = f2h(acc[ti][nt][3] + b3);
                *(ushort4*)&thetaT[((size_t)b * Nn + n) * Cin + ol] = v;
            }
        } else {                                   // g / phi: 2x2 maxpool
            const float* bb = (seg == 0 ? g_b : ph_b);
            float b0 = bb[ol], b1 = bb[ol + 1], b2 = bb[ol + 2], b3 = bb[ol + 3];
            #pragma unroll
            for (int pp = 0; pp < 2; ++pp) {
                float pm[4];
                #pragma unroll
                for (int r = 0; r < 4; ++r) {
                    float m = fmaxf(acc[ti][pp][r], acc[ti][pp + 2][r]);
                    pm[r] = fmaxf(m, __shfl_xor(m, 1, 64));
                }
                int np = ty * 32 + tx * 16 + pp * 8 + (l16 >> 1);
                if ((l16 & 1) == 0) {
                    if (seg == 0) {                // g -> bf16 [o][np] (V dtype)
                        gPc[((size_t)b * Cin + ol + 0) * Npl + np] = f2bf(pm[0] + b0);
                        gPc[((size_t)b * Cin + ol + 1) * Npl + np] = f2bf(pm[1] + b1);
                        gPc[((size_t)b * Cin + ol + 2) * Npl + np] = f2bf(pm[2] + b2);
                        gPc[((size_t)b * Cin + ol + 3) * Npl + np] = f2bf(pm[3] + b3);
                    } else {                       // phi -> fp16 [np][o]
                        ushort4 v;
                        v.x = f2h(pm[0] + b0); v.y = f2h(pm[1] + b1);
                        v.z = f2h(pm[2] + b2); v.w = f2h(pm[3] + b3);
                        *(ushort4*)&phiPt[((size_t)b * Npl + np) * Cin + ol] = v;
                    }
                }
            }
        }
    }
}

// ---------------------------------------------------------------------------
// stage one shared 64-key chunk into buffer sel: waves 0-3 -> K, 4-7 -> V^T.
// ---------------------------------------------------------------------------
__device__ __forceinline__ void stage_kv(
    unsigned short* smem, int sel, int chg, int b, int grp, int wq,
    int mK, int gK, int cV, int gV,
    const unsigned short* __restrict__ phiPt,
    const unsigned short* __restrict__ gPc)
{
    unsigned short* Kb = smem + sel * 16384;
    if (grp == 0) {
        #pragma unroll
        for (int j = 0; j < 4; ++j) {
            int slot = wq * 4 + j;            // 16 slots x 1KB (4 key rows)
            int m  = slot * 4 + mK;
            int gs = gK ^ (m & 7);            // swizzled SOURCE granule
            gload_lds16(&phiPt[((size_t)b * Npl + chg * 64 + m) * Cin + gs * 8],
                        &Kb[slot * 512]);
        }
    } else {
        unsigned short* Vb = Kb + 8192;
        #pragma unroll
        for (int j = 0; j < 4; ++j) {
            int slot = wq * 4 + j;            // 16 slots x 1KB (8 chan rows)
            int c  = slot * 8 + cV;
            int gs = gV ^ (c & 7);
            gload_lds16(&gPc[((size_t)b * Cin + c) * Npl + chg * 64 + gs * 8],
                        &Vb[slot * 512]);
        }
    }
}

// exp + in-register redistribution of one q-tile's S^T into PV A-frag
__device__ __forceinline__ short8 pack_pf(floatx4 s0, floatx4 s1, float& liq) {
    float e0[4], e1[4];
    #pragma unroll
    for (int r = 0; r < 4; ++r) {
        e0[r] = __expf(s0[r] - 20.0f);
        e1[r] = __expf(s1[r] - 20.0f);
        liq += e0[r] + e1[r];
    }
    unsigned int a0 = cvtpk_bf16(e0[0], e0[1]);
    unsigned int a1 = cvtpk_bf16(e1[0], e1[1]);
    unsigned int b0 = cvtpk_bf16(e0[2], e0[3]);
    unsigned int b1 = cvtpk_bf16(e1[2], e1[3]);
    asm volatile("v_permlane32_swap_b32 %0, %1" : "+v"(a0), "+v"(a1));
    asm volatile("v_permlane16_swap_b32 %0, %1" : "+v"(a0), "+v"(a1));
    asm volatile("v_permlane32_swap_b32 %0, %1" : "+v"(b0), "+v"(b1));
    asm volatile("v_permlane16_swap_b32 %0, %1" : "+v"(b0), "+v"(b1));
    uint4 pw; pw.x = a0; pw.y = b0; pw.z = a1; pw.w = b1;
    return __builtin_bit_cast(short8, pw);
}

// ---------------------------------------------------------------------------
// Kernel 2 (R20): fused attention + W conv + BN + residual, 512 threads,
// 128 queries/block (R19 kf/vf-reuse) + T15 CHUNK SOFTWARE-PIPELINE:
// iter ch: stage(ch+3) -> QK(ch+1) -> PV(ch) [independent, hides QK MFMA
// latency] -> exp/pack(ch+1). R19 was serial QK->exp->PV at 2 waves/SIMD
// (MfmaUtil 17, VALUBusy 30: intra-wave dep chain, no TLP to hide it).
// vmcnt ledger (4 issues/wave/chunk): prologue Q8+st12 -> vmcnt(8)=chunk0;
// pre-loop vmcnt(4)=chunk1; iter ch<=12 vmcnt(4)=chunk ch+2; ch==13
// vmcnt(0)=chunk15; no barrier after ch=13. Buffer WAR mod-4 verified.
// ---------------------------------------------------------------------------
#define SSHIFT 20.0f

__global__ __launch_bounds__(512, 2) void k_attn_out(
    const unsigned short* __restrict__ thetaT,
    const unsigned short* __restrict__ phiPt,
    const unsigned short* __restrict__ gPc,
    const unsigned short* __restrict__ Wh,
    const float* __restrict__ cvec,
    const float* __restrict__ x,
    float* __restrict__ out)
{
    __shared__ __align__(16) unsigned short smem[65536];   // 128 KB
    // phase 1: buf[sel] = smem + sel*16384 shorts (Ks 16KB + Vt 16KB), sel=ch&3
    // combine: cbuf f32[8*64*33] = 67.6 KB over dead bufs
    // phase 2: Ys = smem[0..16384) shorts (32KB), Ws = smem+16384 (64KB)

    const int t    = threadIdx.x;
    const int w    = t >> 6;          // 0..7
    const int wq   = w & 3;           // query 32-block
    const int grp  = w >> 2;          // key half within chunk
    const int l    = t & 63;
    const int quad = l >> 4;
    const int l16  = l & 15;
    const int bid  = blockIdx.x;
    const int wid  = (bid & 7) * 32 + (bid >> 3);   // batch b -> XCD b (256=8*32)
    const int b    = wid >> 5;
    const int qb   = wid & 31;
    const int n0   = qb * 128;

    // Q fragments for 2 q-tiles, loaded ONCE; asm pins in VGPRs
    uint4 qr0[4], qr1[4];
    #pragma unroll
    for (int kd = 0; kd < 4; ++kd) {
        qr0[kd] = *(const uint4*)&thetaT[((size_t)b * Nn + n0 + wq * 32 + l16) * Cin
                                         + kd * 32 + quad * 8];
        qr1[kd] = *(const uint4*)&thetaT[((size_t)b * Nn + n0 + wq * 32 + 16 + l16) * Cin
                                         + kd * 32 + quad * 8];
    }
    #pragma unroll
    for (int kd = 0; kd < 4; ++kd) {
        asm volatile("" : "+v"(qr0[kd].x), "+v"(qr0[kd].y), "+v"(qr0[kd].z), "+v"(qr0[kd].w));
        asm volatile("" : "+v"(qr1[kd].x), "+v"(qr1[kd].y), "+v"(qr1[kd].z), "+v"(qr1[kd].w));
    }
    half8 qf0[4], qf1[4];
    #pragma unroll
    for (int kd = 0; kd < 4; ++kd) {
        qf0[kd] = __builtin_bit_cast(half8, qr0[kd]);
        qf1[kd] = __builtin_bit_cast(half8, qr1[kd]);
    }

    floatx4 yacc0[8] = {}, yacc1[8] = {};
    float liq0 = 0.f, liq1 = 0.f;

    const int mK = l >> 4;            // staging lane decomposition
    const int gK = l & 15;
    const int cV = l >> 3;
    const int gV = l & 7;

    // prologue: stage chunks 0,1,2 (12 issues/wave after 8 Q loads)
    #pragma unroll
    for (int pc = 0; pc < 3; ++pc)
        stage_kv(smem, pc, pc, b, grp, wq, mK, gK, cV, gV, phiPt, gPc);
    asm volatile("s_waitcnt vmcnt(8)" ::: "memory");   // Q + chunk0 retired
    __builtin_amdgcn_s_barrier();

    // pre-loop: QK(0) + pack -> pfA (chunk 0)
    short8 pfA0, pfA1;
    {
        const unsigned short* Ks = smem;
        floatx4 s00[2] = {}, s10[2] = {};
        #pragma unroll
        for (int mtl = 0; mtl < 2; ++mtl) {
            int mt = grp * 2 + mtl;
            #pragma unroll
            for (int kd = 0; kd < 4; ++kd) {
                half8 kf = *(const half8*)&Ks[(mt * 16 + l16) * 128
                                              + (((kd * 4 + quad) ^ (l16 & 7)) << 3)];
                s00[mtl] = __builtin_amdgcn_mfma_f32_16x16x32_f16(kf, qf0[kd], s00[mtl], 0, 0, 0);
                s10[mtl] = __builtin_amdgcn_mfma_f32_16x16x32_f16(kf, qf1[kd], s10[mtl], 0, 0, 0);
            }
        }
        pfA0 = pack_pf(s00[0], s00[1], liq0);
        pfA1 = pack_pf(s10[0], s10[1], liq1);
    }
    asm volatile("s_waitcnt vmcnt(4)" ::: "memory");   // chunk1 published
    __builtin_amdgcn_s_barrier();

    for (int ch = 0; ch < 16; ++ch) {
        if (ch < 13)                              // prefetch 3 chunks ahead
            stage_kv(smem, (ch + 3) & 3, ch + 3, b, grp, wq, mK, gK, cV, gV, phiPt, gPc);

        // (1) QK^T of NEXT chunk (issues first; results consumed after PV)
        floatx4 s0n[2] = {}, s1n[2] = {};
        if (ch < 15) {
            const unsigned short* Ksn = smem + ((ch + 1) & 3) * 16384;
            #pragma unroll
            for (int mtl = 0; mtl < 2; ++mtl) {
                int mt = grp * 2 + mtl;
                #pragma unroll
                for (int kd = 0; kd < 4; ++kd) {
                    half8 kf = *(const half8*)&Ksn[(mt * 16 + l16) * 128
                                                   + (((kd * 4 + quad) ^ (l16 & 7)) << 3)];
                    s0n[mtl] = __builtin_amdgcn_mfma_f32_16x16x32_f16(kf, qf0[kd], s0n[mtl], 0, 0, 0);
                    s1n[mtl] = __builtin_amdgcn_mfma_f32_16x16x32_f16(kf, qf1[kd], s1n[mtl], 0, 0, 0);
                }
            }
        }

        // (2) PV of CURRENT chunk (independent of QK(ch+1) -> hides latency)
        {
            const unsigned short* Vt = smem + (ch & 3) * 16384 + 8192;
            #pragma unroll
            for (int ct = 0; ct < 8; ++ct) {
                short8 vf = *(const short8*)&Vt[(ct * 16 + l16) * 64
                                                + (((grp * 4 + quad) ^ (l16 & 7)) << 3)];
                yacc0[ct] = __builtin_amdgcn_mfma_f32_16x16x32_bf16(pfA0, vf, yacc0[ct], 0, 0, 0);
                yacc1[ct] = __builtin_amdgcn_mfma_f32_16x16x32_bf16(pfA1, vf, yacc1[ct], 0, 0, 0);
            }
        }

        // (3) exp/pack of next chunk (QK MFMAs have had PV's issue window)
        if (ch < 15) {
            pfA0 = pack_pf(s0n[0], s0n[1], liq0);
            pfA1 = pack_pf(s1n[0], s1n[1], liq1);
        }

        // counted publish of chunk ch+2 (never drain to 0 mid-loop)
        if (ch <= 12)      asm volatile("s_waitcnt vmcnt(4)" ::: "memory");
        else if (ch == 13) asm volatile("s_waitcnt vmcnt(0)" ::: "memory");
        if (ch <= 13) __builtin_amdgcn_s_barrier();
    }

    // ------- cross-group combine (once) -------
    liq0 += __shfl_xor(liq0, 16, 64);
    liq0 += __shfl_xor(liq0, 32, 64);
    liq1 += __shfl_xor(liq1, 16, 64);
    liq1 += __shfl_xor(liq1, 32, 64);

    __syncthreads();                          // all phase-1 LDS reads done
    float* cbuf = (float*)smem;
    const int ci0 = ((wq * 2 + 0) * 64 + l) * 33;   // pad 33 -> 2-way banks
    const int ci1 = ((wq * 2 + 1) * 64 + l) * 33;
    if (grp == 1) {
        #pragma unroll
        for (int ct = 0; ct < 8; ++ct)
            #pragma unroll
            for (int r = 0; r < 4; ++r) {
                cbuf[ci0 + ct * 4 + r] = yacc0[ct][r];
                cbuf[ci1 + ct * 4 + r] = yacc1[ct][r];
            }
        cbuf[ci0 + 32] = liq0;
        cbuf[ci1 + 32] = liq1;
    }
    __syncthreads();
    if (grp == 0) {
        #pragma unroll
        for (int ct = 0; ct < 8; ++ct)
            #pragma unroll
            for (int r = 0; r < 4; ++r) {
                yacc0[ct][r] += cbuf[ci0 + ct * 4 + r];
                yacc1[ct][r] += cbuf[ci1 + ct * 4 + r];
            }
        liq0 += cbuf[ci0 + 32];
        liq1 += cbuf[ci1 + 32];
    }
    __syncthreads();                          // combine region dead

    // ------- phase 2: out = Wh @ y + cvec + x -------
    // stage full Wh (256x128 fp16, 64 KB) via DMA at smem+16384
    {
        unsigned short* Ws = smem + 16384;
        #pragma unroll
        for (int j = 0; j < 8; ++j) {
            int slot = w * 8 + j;             // 0..63, 4 rows each
            int row  = slot * 4 + mK;         // 0..255
            int gs   = gK ^ (row & 7);
            gload_lds16(&Wh[(size_t)row * Cin + gs * 8], &Ws[slot * 512]);
        }
    }

    // normalized y -> Ys fp16 [128 q][128 c] (group 0), packed 4B writes
    if (grp == 0) {
        unsigned int* Yw = (unsigned int*)smem;
        #pragma unroll
        for (int r = 0; r < 4; ++r) {
            float lr0 = __shfl(liq0, quad * 4 + r, 64);
            float lr1 = __shfl(liq1, quad * 4 + r, 64);
            float il0 = 1.0f / lr0;
            float il1 = 1.0f / lr1;
            int q0 = wq * 32 + quad * 4 + r;
            int q1 = q0 + 16;
            #pragma unroll
            for (int ct = 0; ct < 8; ++ct) {
                unsigned int h0 = f2h(yacc0[ct][r] * il0);
                unsigned int p0 = (unsigned int)__shfl_xor((int)h0, 1, 64);
                unsigned int h1 = f2h(yacc1[ct][r] * il1);
                unsigned int p1 = (unsigned int)__shfl_xor((int)h1, 1, 64);
                if ((l16 & 1) == 0) {
                    int g = ct * 2 + (l16 >> 3);
                    Yw[q0 * 64 + (((g ^ (q0 & 7)) << 2) | ((l16 & 7) >> 1))] = h0 | (p0 << 16);
                    Yw[q1 * 64 + (((g ^ (q1 & 7)) << 2) | ((l16 & 7) >> 1))] = h1 | (p1 << 16);
                }
            }
        }
    }
    asm volatile("s_waitcnt vmcnt(0)" ::: "memory");
    __syncthreads();

    const unsigned short* Ys = smem;
    const unsigned short* Ws = smem + 16384;

    // each wave: 32 output rows (w*32..+31) x 128 queries (8 nt tiles)
    half8 af[2][4];
    #pragma unroll
    for (int mt = 0; mt < 2; ++mt)
        #pragma unroll
        for (int kd = 0; kd < 4; ++kd) {
            int row = w * 32 + mt * 16 + l16;
            af[mt][kd] = *(const half8*)&Ws[row * 128
                                            + (((kd * 4 + quad) ^ (l16 & 7)) << 3)];
        }

    floatx4 acc[2][8] = {};
    #pragma unroll
    for (int nt = 0; nt < 8; ++nt) {
        half8 bfr[4];
        #pragma unroll
        for (int kd = 0; kd < 4; ++kd)
            bfr[kd] = *(const half8*)&Ys[(nt * 16 + l16) * 128
                                         + (((kd * 4 + quad) ^ (l16 & 7)) << 3)];
        #pragma unroll
        for (int mt = 0; mt < 2; ++mt)
            #pragma unroll
            for (int kd = 0; kd < 4; ++kd)
                acc[mt][nt] = __builtin_amdgcn_mfma_f32_16x16x32_f16(af[mt][kd], bfr[kd], acc[mt][nt], 0, 0, 0);
    }

    #pragma unroll
    for (int mt = 0; mt < 2; ++mt) {
        #pragma unroll
        for (int r = 0; r < 4; ++r) {
            int o = w * 32 + mt * 16 + quad * 4 + r;
            float cv = cvec[o];
            #pragma unroll
            for (int nt = 0; nt < 8; ++nt) {
                size_t gi = ((size_t)(b * Cc + o)) * Nn + n0 + nt * 16 + l16;
                out[gi] = acc[mt][nt][r] + cv + x[gi];
            }
        }
    }
}

// ---------------------------------------------------------------------------
extern "C" void kernel_launch(void* const* d_in, const int* in_sizes, int n_in,
                              void* d_out, int out_size, void* d_ws, size_t ws_size,
                              hipStream_t stream) {
    const float* x    = (const float*)d_in[0];
    const float* g_w  = (const float*)d_in[1];
    const float* g_b  = (const float*)d_in[2];
    const float* th_w = (const float*)d_in[3];
    const float* th_b = (const float*)d_in[4];
    const float* ph_w = (const float*)d_in[5];
    const float* ph_b = (const float*)d_in[6];
    const float* W_w  = (const float*)d_in[7];
    const float* W_b  = (const float*)d_in[8];
    const float* gmm  = (const float*)d_in[9];
    const float* bta  = (const float*)d_in[10];
    const float* mmn  = (const float*)d_in[11];
    const float* vvr  = (const float*)d_in[12];
    float* out = (float*)d_out;

    unsigned short* thetaT = (unsigned short*)d_ws;      // 8 MB fp16
    unsigned short* phiPt  = thetaT + (size_t)4194304;   // 2 MB fp16
    unsigned short* gPc    = phiPt + (size_t)1048576;    // 2 MB bf16
    unsigned short* Wh     = gPc + (size_t)1048576;      // 64 KB
    unsigned short* gWh    = Wh + 32768;
    unsigned short* thWh   = gWh + 32768;
    unsigned short* thWl   = thWh + 32768;
    unsigned short* phWh   = thWl + 32768;
    unsigned short* phWl   = phWh + 32768;
    float*          cvec   = (float*)(phWl + 32768);     // 1 KB

    k_prep<<<dim3(512), dim3(256), 0, stream>>>(
        g_w, th_w, ph_w, W_w, W_b, gmm, bta, mmn, vvr,
        gWh, thWh, thWl, phWh, phWl, Wh, cvec);
    k_conv3<<<dim3(Bn * 64), dim3(512), 0, stream>>>(
        x, gWh, thWh, thWl, phWh, phWl, g_b, th_b, ph_b, thetaT, gPc, phiPt);
    k_attn_out<<<dim3(Bn * 32), dim3(512), 0, stream>>>(
        thetaT, phiPt, gPc, Wh, cvec, x, out);
}

// Round 14
// 153.961 us; speedup vs baseline: 1.0191x; 1.0027x over previous
//
#include <hip/hip_runtime.h>
#include <math.h>

// Problem constants
#define Bn   8
#define Cc   256     // input channels
#define Cin  128     // inter channels
#define Hh   64
#define Ww   64
#define Nn   4096    // H*W
#define Npl  1024    // pooled pixels (32*32)
#define EPSf 1e-5f

typedef __attribute__((ext_vector_type(8))) short    short8;   // 8 bf16
typedef __attribute__((ext_vector_type(8))) _Float16 half8;    // 8 fp16
typedef __attribute__((ext_vector_type(4))) float    floatx4;  // MFMA C/D

__device__ __forceinline__ unsigned short f2bf(float f) {
    unsigned int u = __float_as_uint(f);
    u += 0x7fffu + ((u >> 16) & 1u);
    return (unsigned short)(u >> 16);
}
__device__ __forceinline__ unsigned short f2h(float f) {
    _Float16 h = (_Float16)f;
    return __builtin_bit_cast(unsigned short, h);
}
__device__ __forceinline__ float h2f(unsigned short u) {
    return (float)__builtin_bit_cast(_Float16, u);
}

// pack two f32 -> bf16 pair (lo=src0, hi=src1); no builtin on gfx950
__device__ __forceinline__ unsigned int cvtpk_bf16(float lo, float hi) {
    unsigned int r;
    asm("v_cvt_pk_bf16_f32 %0, %1, %2" : "=v"(r) : "v"(lo), "v"(hi));
    return r;
}

// async global->LDS DMA, 16B per lane; LDS dest = wave-uniform base + lane*16
__device__ __forceinline__ void gload_lds16(const unsigned short* g, unsigned short* l) {
    __builtin_amdgcn_global_load_lds(
        (const __attribute__((address_space(1))) unsigned int*)g,
        (__attribute__((address_space(3))) unsigned int*)l, 16, 0, 0);
}

// ---------------------------------------------------------------------------
// Kernel 0 (prep): fp16 weight variants.
//  - g/theta/phi stored PRE-PERMUTED into MFMA A-fragment order (R15).
//  - Wh = fp16(W_w * gamma/sqrt(var+eps)) row-major; cvec folded BN bias.
// ---------------------------------------------------------------------------
__global__ __launch_bounds__(256) void k_prep(
    const float* __restrict__ g_w, const float* __restrict__ th_w,
    const float* __restrict__ ph_w,
    const float* __restrict__ W_w, const float* __restrict__ W_b,
    const float* __restrict__ gamma, const float* __restrict__ beta,
    const float* __restrict__ mean,  const float* __restrict__ var,
    unsigned short* __restrict__ gWh,
    unsigned short* __restrict__ thWh, unsigned short* __restrict__ thWl,
    unsigned short* __restrict__ phWh, unsigned short* __restrict__ phWl,
    unsigned short* __restrict__ Wh, float* __restrict__ cvec)
{
    int i = blockIdx.x * 256 + threadIdx.x;
    if (i < 98304) {                          // 3 x 128 x 256 conv weights
        int seg = i >> 15;                    // 0:g 1:theta 2:phi
        int idx = i & 32767;
        int o = idx >> 8;                     // 0..127 output channel
        int c = idx & 255;                    // 0..255 input channel
        // fragment-order position (bijective)
        int p = (((o >> 4) * 8 + (c >> 5)) * 64
                 + ((c >> 3) & 3) * 16 + (o & 15)) * 8 + (c & 7);
        float v = (seg == 0 ? g_w : (seg == 1 ? th_w : ph_w))[idx];
        unsigned short hi = f2h(v);
        if (seg == 0) gWh[p] = hi;
        else {
            (seg == 1 ? thWh : phWh)[p] = hi;
            (seg == 1 ? thWl : phWl)[p] = f2h(v - h2f(hi));
        }
    } else {
        int j = i - 98304;                    // 0..32767 : W fold (256x128)
        int o = j >> 7;
        float inv = gamma[o] * rsqrtf(var[o] + EPSf);
        Wh[j] = f2h(W_w[j] * inv);
        if (j < Cc) {
            float invi = gamma[j] * rsqrtf(var[j] + EPSf);
            cvec[j] = (W_b[j] - mean[j]) * invi + beta[j];
        }
    }
}

// ---------------------------------------------------------------------------
// Kernel 1 (R22 = R21 with sigma hoisted): fused conv1x1 g/theta/phi,
// 64-px tiles, 512 threads / 8 waves, 3 output-tiles per wave (seg==ti).
// 16B-granule rotation sigma = 2*(p4&3) + (p4>>2) on the channel axis
// (constant across the i-loop since px>>2 == p4). Write banks: exact
// 2-way (free; was 8-way / 2.36M SQ_LDS_BANK_CONFLICT). Read slots:
// enumerated uniform 8 lanes/slot. Rotation in 16B granules -> b128
// blocks contiguous (wrap preserves granule: start mult-of-4 words);
// bijective per row -> bit-identical numerics.
// ---------------------------------------------------------------------------
#define XPAD 264

__global__ __launch_bounds__(512, 4) void k_conv3(
    const float* __restrict__ x,
    const unsigned short* __restrict__ gWh,
    const unsigned short* __restrict__ thWh, const unsigned short* __restrict__ thWl,
    const unsigned short* __restrict__ phWh, const unsigned short* __restrict__ phWl,
    const float* __restrict__ g_b, const float* __restrict__ th_b,
    const float* __restrict__ ph_b,
    unsigned short* __restrict__ thetaT,
    unsigned short* __restrict__ gPc,
    unsigned short* __restrict__ phiPt)
{
    __shared__ __align__(16) unsigned short Xhi[64 * XPAD];   // 33 KB
    __shared__ __align__(16) unsigned short Xlo[64 * XPAD];   // 33 KB

    const int t    = threadIdx.x;
    const int w    = t >> 6;          // 0..7
    const int l    = t & 63;
    const int quad = l >> 4;
    const int l16  = l & 15;
    const int b    = blockIdx.x >> 6;
    const int tile = blockIdx.x & 63;
    const int ty   = tile >> 1;
    const int tx   = tile & 1;

    {
        const float4* xg = (const float4*)x;
        unsigned int* XhiW = (unsigned int*)Xhi;
        unsigned int* XloW = (unsigned int*)Xlo;
        #pragma unroll
        for (int it = 0; it < 4; ++it) {
            int idx = t + 512 * it;          // 0..2047
            int c2  = idx >> 4;
            int p4  = idx & 15;
            int n   = (2 * ty + (p4 >> 3)) * Ww + tx * 32 + (p4 & 7) * 4;
            // sigma(px) is constant over i: px>>2 == p4, px>>4 == p4>>2
            int sg  = 2 * (p4 & 3) + (p4 >> 2);
            int cw  = (c2 + 4 * sg) & 127;   // rotated word (same for i=0..3)
            float4 va = xg[((size_t)(b * Cc + 2 * c2) * Nn + n) >> 2];
            float4 vb = xg[((size_t)(b * Cc + 2 * c2 + 1) * Nn + n) >> 2];
            const float fa[4] = {va.x, va.y, va.z, va.w};
            const float fb[4] = {vb.x, vb.y, vb.z, vb.w};
            #pragma unroll
            for (int i = 0; i < 4; ++i) {
                int px = p4 * 4 + i;
                unsigned short ha = f2h(fa[i]), hb = f2h(fb[i]);
                unsigned short la = f2h(fa[i] - h2f(ha));
                unsigned short lb = f2h(fb[i] - h2f(hb));
                XhiW[px * 132 + cw] = (unsigned int)ha | ((unsigned int)hb << 16);
                XloW[px * 132 + cw] = (unsigned int)la | ((unsigned int)lb << 16);
            }
        }
    }
    __syncthreads();

    floatx4 acc[3][4] = {};

    #pragma unroll 2
    for (int kd = 0; kd < 8; ++kd) {
        half8 bhi[4], blo[4];
        #pragma unroll
        for (int nt = 0; nt < 4; ++nt) {
            int row = nt * 16 + l16;
            int sg  = 2 * ((row >> 2) & 3) + (row >> 4);    // sigma(row)
            int off = (kd * 32 + quad * 8 + 8 * sg) & 255;  // rotated shorts
            bhi[nt] = *(const half8*)&Xhi[row * XPAD + off];
            blo[nt] = *(const half8*)&Xlo[row * XPAD + off];
        }
        #pragma unroll
        for (int ti = 0; ti < 3; ++ti) {
            int seg = ti;                                // ot = w + 8*ti
            size_t aoff = (size_t)((w * 8 + kd) * 512 + l * 8);   // frag order
            const unsigned short* wh = (seg == 0 ? gWh : (seg == 1 ? thWh : phWh));
            half8 ah = *(const half8*)&wh[aoff];
            #pragma unroll
            for (int nt = 0; nt < 4; ++nt)
                acc[ti][nt] = __builtin_amdgcn_mfma_f32_16x16x32_f16(ah, bhi[nt], acc[ti][nt], 0, 0, 0);
            if (seg != 0) {
                const unsigned short* wl = (seg == 1 ? thWl : phWl);
                half8 al = *(const half8*)&wl[aoff];
                #pragma unroll
                for (int nt = 0; nt < 4; ++nt) {
                    acc[ti][nt] = __builtin_amdgcn_mfma_f32_16x16x32_f16(ah, blo[nt], acc[ti][nt], 0, 0, 0);
                    acc[ti][nt] = __builtin_amdgcn_mfma_f32_16x16x32_f16(al, bhi[nt], acc[ti][nt], 0, 0, 0);
                }
            }
        }
    }

    // epilogue: D[row=quad*4+r][col=l16]; per wave channels w*16+quad*4..+3
    #pragma unroll
    for (int ti = 0; ti < 3; ++ti) {
        int seg = ti;
        int ol  = w * 16 + quad * 4;
        if (seg == 1) {                            // theta -> fp16 [n][o]
            float b0 = th_b[ol], b1 = th_b[ol + 1], b2 = th_b[ol + 2], b3 = th_b[ol + 3];
            #pragma unroll
            for (int nt = 0; nt < 4; ++nt) {
                int n = (2 * ty + (nt >> 1)) * Ww + tx * 32 + (nt & 1) * 16 + l16;
                ushort4 v;
                v.x = f2h(acc[ti][nt][0] + b0);
                v.y = f2h(acc[ti][nt][1] + b1);
                v.z = f2h(acc[ti][nt][2] + b2);
                v.w = f2h(acc[ti][nt][3] + b3);
                *(ushort4*)&thetaT[((size_t)b * Nn + n) * Cin + ol] = v;
            }
        } else {                                   // g / phi: 2x2 maxpool
            const float* bb = (seg == 0 ? g_b : ph_b);
            float b0 = bb[ol], b1 = bb[ol + 1], b2 = bb[ol + 2], b3 = bb[ol + 3];
            #pragma unroll
            for (int pp = 0; pp < 2; ++pp) {
                float pm[4];
                #pragma unroll
                for (int r = 0; r < 4; ++r) {
                    float m = fmaxf(acc[ti][pp][r], acc[ti][pp + 2][r]);
                    pm[r] = fmaxf(m, __shfl_xor(m, 1, 64));
                }
                int np = ty * 32 + tx * 16 + pp * 8 + (l16 >> 1);
                if ((l16 & 1) == 0) {
                    if (seg == 0) {                // g -> bf16 [o][np] (V dtype)
                        gPc[((size_t)b * Cin + ol + 0) * Npl + np] = f2bf(pm[0] + b0);
                        gPc[((size_t)b * Cin + ol + 1) * Npl + np] = f2bf(pm[1] + b1);
                        gPc[((size_t)b * Cin + ol + 2) * Npl + np] = f2bf(pm[2] + b2);
                        gPc[((size_t)b * Cin + ol + 3) * Npl + np] = f2bf(pm[3] + b3);
                    } else {                       // phi -> fp16 [np][o]
                        ushort4 v;
                        v.x = f2h(pm[0] + b0); v.y = f2h(pm[1] + b1);
                        v.z = f2h(pm[2] + b2); v.w = f2h(pm[3] + b3);
                        *(ushort4*)&phiPt[((size_t)b * Npl + np) * Cin + ol] = v;
                    }
                }
            }
        }
    }
}

// ---------------------------------------------------------------------------
// stage one shared 64-key chunk into buffer sel: waves 0-3 -> K, 4-7 -> V^T.
// ---------------------------------------------------------------------------
__device__ __forceinline__ void stage_kv(
    unsigned short* smem, int sel, int chg, int b, int grp, int wq,
    int mK, int gK, int cV, int gV,
    const unsigned short* __restrict__ phiPt,
    const unsigned short* __restrict__ gPc)
{
    unsigned short* Kb = smem + sel * 16384;
    if (grp == 0) {
        #pragma unroll
        for (int j = 0; j < 4; ++j) {
            int slot = wq * 4 + j;            // 16 slots x 1KB (4 key rows)
            int m  = slot * 4 + mK;
            int gs = gK ^ (m & 7);            // swizzled SOURCE granule
            gload_lds16(&phiPt[((size_t)b * Npl + chg * 64 + m) * Cin + gs * 8],
                        &Kb[slot * 512]);
        }
    } else {
        unsigned short* Vb = Kb + 8192;
        #pragma unroll
        for (int j = 0; j < 4; ++j) {
            int slot = wq * 4 + j;            // 16 slots x 1KB (8 chan rows)
            int c  = slot * 8 + cV;
            int gs = gV ^ (c & 7);
            gload_lds16(&gPc[((size_t)b * Cin + c) * Npl + chg * 64 + gs * 8],
                        &Vb[slot * 512]);
        }
    }
}

// exp + in-register redistribution of one q-tile's S^T into PV A-frag
__device__ __forceinline__ short8 pack_pf(floatx4 s0, floatx4 s1, float& liq) {
    float e0[4], e1[4];
    #pragma unroll
    for (int r = 0; r < 4; ++r) {
        e0[r] = __expf(s0[r] - 20.0f);
        e1[r] = __expf(s1[r] - 20.0f);
        liq += e0[r] + e1[r];
    }
    unsigned int a0 = cvtpk_bf16(e0[0], e0[1]);
    unsigned int a1 = cvtpk_bf16(e1[0], e1[1]);
    unsigned int b0 = cvtpk_bf16(e0[2], e0[3]);
    unsigned int b1 = cvtpk_bf16(e1[2], e1[3]);
    asm volatile("v_permlane32_swap_b32 %0, %1" : "+v"(a0), "+v"(a1));
    asm volatile("v_permlane16_swap_b32 %0, %1" : "+v"(a0), "+v"(a1));
    asm volatile("v_permlane32_swap_b32 %0, %1" : "+v"(b0), "+v"(b1));
    asm volatile("v_permlane16_swap_b32 %0, %1" : "+v"(b0), "+v"(b1));
    uint4 pw; pw.x = a0; pw.y = b0; pw.z = a1; pw.w = b1;
    return __builtin_bit_cast(short8, pw);
}

// ---------------------------------------------------------------------------
// Kernel 2 (R20, proven best): fused attention + W conv + BN + residual,
// 512 threads, 128 queries/block (kf/vf reuse) + chunk software-pipeline:
// iter ch: stage(ch+3) -> QK(ch+1) -> PV(ch) -> exp/pack(ch+1).
// vmcnt ledger: prologue Q8+st12 -> vmcnt(8)=chunk0; pre-loop vmcnt(4)=
// chunk1; iter ch<=12 vmcnt(4)=chunk ch+2; ch==13 vmcnt(0); no barrier
// after ch=13. Buffer WAR mod-4 verified.
// ---------------------------------------------------------------------------
#define SSHIFT 20.0f

__global__ __launch_bounds__(512, 2) void k_attn_out(
    const unsigned short* __restrict__ thetaT,
    const unsigned short* __restrict__ phiPt,
    const unsigned short* __restrict__ gPc,
    const unsigned short* __restrict__ Wh,
    const float* __restrict__ cvec,
    const float* __restrict__ x,
    float* __restrict__ out)
{
    __shared__ __align__(16) unsigned short smem[65536];   // 128 KB
    // phase 1: buf[sel] = smem + sel*16384 shorts (Ks 16KB + Vt 16KB), sel=ch&3
    // combine: cbuf f32[8*64*33] = 67.6 KB over dead bufs
    // phase 2: Ys = smem[0..16384) shorts (32KB), Ws = smem+16384 (64KB)

    const int t    = threadIdx.x;
    const int w    = t >> 6;          // 0..7
    const int wq   = w & 3;           // query 32-block
    const int grp  = w >> 2;          // key half within chunk
    const int l    = t & 63;
    const int quad = l >> 4;
    const int l16  = l & 15;
    const int bid  = blockIdx.x;
    const int wid  = (bid & 7) * 32 + (bid >> 3);   // batch b -> XCD b (256=8*32)
    const int b    = wid >> 5;
    const int qb   = wid & 31;
    const int n0   = qb * 128;

    // Q fragments for 2 q-tiles, loaded ONCE; asm pins in VGPRs
    uint4 qr0[4], qr1[4];
    #pragma unroll
    for (int kd = 0; kd < 4; ++kd) {
        qr0[kd] = *(const uint4*)&thetaT[((size_t)b * Nn + n0 + wq * 32 + l16) * Cin
                                         + kd * 32 + quad * 8];
        qr1[kd] = *(const uint4*)&thetaT[((size_t)b * Nn + n0 + wq * 32 + 16 + l16) * Cin
                                         + kd * 32 + quad * 8];
    }
    #pragma unroll
    for (int kd = 0; kd < 4; ++kd) {
        asm volatile("" : "+v"(qr0[kd].x), "+v"(qr0[kd].y), "+v"(qr0[kd].z), "+v"(qr0[kd].w));
        asm volatile("" : "+v"(qr1[kd].x), "+v"(qr1[kd].y), "+v"(qr1[kd].z), "+v"(qr1[kd].w));
    }
    half8 qf0[4], qf1[4];
    #pragma unroll
    for (int kd = 0; kd < 4; ++kd) {
        qf0[kd] = __builtin_bit_cast(half8, qr0[kd]);
        qf1[kd] = __builtin_bit_cast(half8, qr1[kd]);
    }

    floatx4 yacc0[8] = {}, yacc1[8] = {};
    float liq0 = 0.f, liq1 = 0.f;

    const int mK = l >> 4;            // staging lane decomposition
    const int gK = l & 15;
    const int cV = l >> 3;
    const int gV = l & 7;

    // prologue: stage chunks 0,1,2 (12 issues/wave after 8 Q loads)
    #pragma unroll
    for (int pc = 0; pc < 3; ++pc)
        stage_kv(smem, pc, pc, b, grp, wq, mK, gK, cV, gV, phiPt, gPc);
    asm volatile("s_waitcnt vmcnt(8)" ::: "memory");   // Q + chunk0 retired
    __builtin_amdgcn_s_barrier();

    // pre-loop: QK(0) + pack -> pfA (chunk 0)
    short8 pfA0, pfA1;
    {
        const unsigned short* Ks = smem;
        floatx4 s00[2] = {}, s10[2] = {};
        #pragma unroll
        for (int mtl = 0; mtl < 2; ++mtl) {
            int mt = grp * 2 + mtl;
            #pragma unroll
            for (int kd = 0; kd < 4; ++kd) {
                half8 kf = *(const half8*)&Ks[(mt * 16 + l16) * 128
                                              + (((kd * 4 + quad) ^ (l16 & 7)) << 3)];
                s00[mtl] = __builtin_amdgcn_mfma_f32_16x16x32_f16(kf, qf0[kd], s00[mtl], 0, 0, 0);
                s10[mtl] = __builtin_amdgcn_mfma_f32_16x16x32_f16(kf, qf1[kd], s10[mtl], 0, 0, 0);
            }
        }
        pfA0 = pack_pf(s00[0], s00[1], liq0);
        pfA1 = pack_pf(s10[0], s10[1], liq1);
    }
    asm volatile("s_waitcnt vmcnt(4)" ::: "memory");   // chunk1 published
    __builtin_amdgcn_s_barrier();

    for (int ch = 0; ch < 16; ++ch) {
        if (ch < 13)                              // prefetch 3 chunks ahead
            stage_kv(smem, (ch + 3) & 3, ch + 3, b, grp, wq, mK, gK, cV, gV, phiPt, gPc);

        // (1) QK^T of NEXT chunk (issues first; results consumed after PV)
        floatx4 s0n[2] = {}, s1n[2] = {};
        if (ch < 15) {
            const unsigned short* Ksn = smem + ((ch + 1) & 3) * 16384;
            #pragma unroll
            for (int mtl = 0; mtl < 2; ++mtl) {
                int mt = grp * 2 + mtl;
                #pragma unroll
                for (int kd = 0; kd < 4; ++kd) {
                    half8 kf = *(const half8*)&Ksn[(mt * 16 + l16) * 128
                                                   + (((kd * 4 + quad) ^ (l16 & 7)) << 3)];
                    s0n[mtl] = __builtin_amdgcn_mfma_f32_16x16x32_f16(kf, qf0[kd], s0n[mtl], 0, 0, 0);
                    s1n[mtl] = __builtin_amdgcn_mfma_f32_16x16x32_f16(kf, qf1[kd], s1n[mtl], 0, 0, 0);
                }
            }
        }

        // (2) PV of CURRENT chunk (independent of QK(ch+1) -> hides latency)
        {
            const unsigned short* Vt = smem + (ch & 3) * 16384 + 8192;
            #pragma unroll
            for (int ct = 0; ct < 8; ++ct) {
                short8 vf = *(const short8*)&Vt[(ct * 16 + l16) * 64
                                                + (((grp * 4 + quad) ^ (l16 & 7)) << 3)];
                yacc0[ct] = __builtin_amdgcn_mfma_f32_16x16x32_bf16(pfA0, vf, yacc0[ct], 0, 0, 0);
                yacc1[ct] = __builtin_amdgcn_mfma_f32_16x16x32_bf16(pfA1, vf, yacc1[ct], 0, 0, 0);
            }
        }

        // (3) exp/pack of next chunk (QK MFMAs have had PV's issue window)
        if (ch < 15) {
            pfA0 = pack_pf(s0n[0], s0n[1], liq0);
            pfA1 = pack_pf(s1n[0], s1n[1], liq1);
        }

        // counted publish of chunk ch+2 (never drain to 0 mid-loop)
        if (ch <= 12)      asm volatile("s_waitcnt vmcnt(4)" ::: "memory");
        else if (ch == 13) asm volatile("s_waitcnt vmcnt(0)" ::: "memory");
        if (ch <= 13) __builtin_amdgcn_s_barrier();
    }

    // ------- cross-group combine (once) -------
    liq0 += __shfl_xor(liq0, 16, 64);
    liq0 += __shfl_xor(liq0, 32, 64);
    liq1 += __shfl_xor(liq1, 16, 64);
    liq1 += __shfl_xor(liq1, 32, 64);

    __syncthreads();                          // all phase-1 LDS reads done
    float* cbuf = (float*)smem;
    const int ci0 = ((wq * 2 + 0) * 64 + l) * 33;   // pad 33 -> 2-way banks
    const int ci1 = ((wq * 2 + 1) * 64 + l) * 33;
    if (grp == 1) {
        #pragma unroll
        for (int ct = 0; ct < 8; ++ct)
            #pragma unroll
            for (int r = 0; r < 4; ++r) {
                cbuf[ci0 + ct * 4 + r] = yacc0[ct][r];
                cbuf[ci1 + ct * 4 + r] = yacc1[ct][r];
            }
        cbuf[ci0 + 32] = liq0;
        cbuf[ci1 + 32] = liq1;
    }
    __syncthreads();
    if (grp == 0) {
        #pragma unroll
        for (int ct = 0; ct < 8; ++ct)
            #pragma unroll
            for (int r = 0; r < 4; ++r) {
                yacc0[ct][r] += cbuf[ci0 + ct * 4 + r];
                yacc1[ct][r] += cbuf[ci1 + ct * 4 + r];
            }
        liq0 += cbuf[ci0 + 32];
        liq1 += cbuf[ci1 + 32];
    }
    __syncthreads();                          // combine region dead

    // ------- phase 2: out = Wh @ y + cvec + x -------
    // stage full Wh (256x128 fp16, 64 KB) via DMA at smem+16384
    {
        unsigned short* Ws = smem + 16384;
        #pragma unroll
        for (int j = 0; j < 8; ++j) {
            int slot = w * 8 + j;             // 0..63, 4 rows each
            int row  = slot * 4 + mK;         // 0..255
            int gs   = gK ^ (row & 7);
            gload_lds16(&Wh[(size_t)row * Cin + gs * 8], &Ws[slot * 512]);
        }
    }

    // normalized y -> Ys fp16 [128 q][128 c] (group 0), packed 4B writes
    if (grp == 0) {
        unsigned int* Yw = (unsigned int*)smem;
        #pragma unroll
        for (int r = 0; r < 4; ++r) {
            float lr0 = __shfl(liq0, quad * 4 + r, 64);
            float lr1 = __shfl(liq1, quad * 4 + r, 64);
            float il0 = 1.0f / lr0;
            float il1 = 1.0f / lr1;
            int q0 = wq * 32 + quad * 4 + r;
            int q1 = q0 + 16;
            #pragma unroll
            for (int ct = 0; ct < 8; ++ct) {
                unsigned int h0 = f2h(yacc0[ct][r] * il0);
                unsigned int p0 = (unsigned int)__shfl_xor((int)h0, 1, 64);
                unsigned int h1 = f2h(yacc1[ct][r] * il1);
                unsigned int p1 = (unsigned int)__shfl_xor((int)h1, 1, 64);
                if ((l16 & 1) == 0) {
                    int g = ct * 2 + (l16 >> 3);
                    Yw[q0 * 64 + (((g ^ (q0 & 7)) << 2) | ((l16 & 7) >> 1))] = h0 | (p0 << 16);
                    Yw[q1 * 64 + (((g ^ (q1 & 7)) << 2) | ((l16 & 7) >> 1))] = h1 | (p1 << 16);
                }
            }
        }
    }
    asm volatile("s_waitcnt vmcnt(0)" ::: "memory");
    __syncthreads();

    const unsigned short* Ys = smem;
    const unsigned short* Ws = smem + 16384;

    // each wave: 32 output rows (w*32..+31) x 128 queries (8 nt tiles)
    half8 af[2][4];
    #pragma unroll
    for (int mt = 0; mt < 2; ++mt)
        #pragma unroll
        for (int kd = 0; kd < 4; ++kd) {
            int row = w * 32 + mt * 16 + l16;
            af[mt][kd] = *(const half8*)&Ws[row * 128
                                            + (((kd * 4 + quad) ^ (l16 & 7)) << 3)];
        }

    floatx4 acc[2][8] = {};
    #pragma unroll
    for (int nt = 0; nt < 8; ++nt) {
        half8 bfr[4];
        #pragma unroll
        for (int kd = 0; kd < 4; ++kd)
            bfr[kd] = *(const half8*)&Ys[(nt * 16 + l16) * 128
                                         + (((kd * 4 + quad) ^ (l16 & 7)) << 3)];
        #pragma unroll
        for (int mt = 0; mt < 2; ++mt)
            #pragma unroll
            for (int kd = 0; kd < 4; ++kd)
                acc[mt][nt] = __builtin_amdgcn_mfma_f32_16x16x32_f16(af[mt][kd], bfr[kd], acc[mt][nt], 0, 0, 0);
    }

    #pragma unroll
    for (int mt = 0; mt < 2; ++mt) {
        #pragma unroll
        for (int r = 0; r < 4; ++r) {
            int o = w * 32 + mt * 16 + quad * 4 + r;
            float cv = cvec[o];
            #pragma unroll
            for (int nt = 0; nt < 8; ++nt) {
                size_t gi = ((size_t)(b * Cc + o)) * Nn + n0 + nt * 16 + l16;
                out[gi] = acc[mt][nt][r] + cv + x[gi];
            }
        }
    }
}

// ---------------------------------------------------------------------------
extern "C" void kernel_launch(void* const* d_in, const int* in_sizes, int n_in,
                              void* d_out, int out_size, void* d_ws, size_t ws_size,
                              hipStream_t stream) {
    const float* x    = (const float*)d_in[0];
    const float* g_w  = (const float*)d_in[1];
    const float* g_b  = (const float*)d_in[2];
    const float* th_w = (const float*)d_in[3];
    const float* th_b = (const float*)d_in[4];
    const float* ph_w = (const float*)d_in[5];
    const float* ph_b = (const float*)d_in[6];
    const float* W_w  = (const float*)d_in[7];
    const float* W_b  = (const float*)d_in[8];
    const float* gmm  = (const float*)d_in[9];
    const float* bta  = (const float*)d_in[10];
    const float* mmn  = (const float*)d_in[11];
    const float* vvr  = (const float*)d_in[12];
    float* out = (float*)d_out;

    unsigned short* thetaT = (unsigned short*)d_ws;      // 8 MB fp16
    unsigned short* phiPt  = thetaT + (size_t)4194304;   // 2 MB fp16
    unsigned short* gPc    = phiPt + (size_t)1048576;    // 2 MB bf16
    unsigned short* Wh     = gPc + (size_t)1048576;      // 64 KB
    unsigned short* gWh    = Wh + 32768;
    unsigned short* thWh   = gWh + 32768;
    unsigned short* thWl   = thWh + 32768;
    unsigned short* phWh   = thWl + 32768;
    unsigned short* phWl   = phWh + 32768;
    float*          cvec   = (float*)(phWl + 32768);     // 1 KB

    k_prep<<<dim3(512), dim3(256), 0, stream>>>(
        g_w, th_w, ph_w, W_w, W_b, gmm, bta, mmn, vvr,
        gWh, thWh, thWl, phWh, phWl, Wh, cvec);
    k_conv3<<<dim3(Bn * 64), dim3(512), 0, stream>>>(
        x, gWh, thWh, thWl, phWh, phWl, g_b, th_b, ph_b, thetaT, gPc, phiPt);
    k_attn_out<<<dim3(Bn * 32), dim3(512), 0, stream>>>(
        thetaT, phiPt, gPc, Wh, cvec, x, out);
}